// Round 1
// baseline (566.631 us; speedup 1.0000x reference)
//
#include <hip/hip_runtime.h>

typedef _Float16 half8 __attribute__((ext_vector_type(8)));
typedef float floatx4 __attribute__((ext_vector_type(4)));

#define AS1 __attribute__((address_space(1)))
#define AS3 __attribute__((address_space(3)))

// ---------------------------------------------------------------------------
// W transpose + fp32->fp16: W [1024][1024] (k,n) -> Wt [1024][1024] (n,k)
// grid (16,16,3), block 256. 64x64 tiles through LDS.
// ---------------------------------------------------------------------------
__global__ __launch_bounds__(256) void wtrans_kernel(
    const float* __restrict__ W0, const float* __restrict__ W1,
    const float* __restrict__ W2, _Float16* __restrict__ Wt)
{
    __shared__ _Float16 t[64 * 72];
    const float* W = (blockIdx.z == 0) ? W0 : (blockIdx.z == 1) ? W1 : W2;
    _Float16* O = Wt + (long)blockIdx.z * 1048576;
    const int tid = threadIdx.x;
    const int kb = blockIdx.y * 64, nb = blockIdx.x * 64;
#pragma unroll
    for (int i = 0; i < 4; i++) {
        int r = (tid >> 4) + i * 16;
        int c = (tid & 15) * 4;
        floatx4 w = *(const floatx4*)&W[(long)(kb + r) * 1024 + nb + c];
#pragma unroll
        for (int j = 0; j < 4; j++) t[(c + j) * 72 + r] = (_Float16)w[j];
    }
    __syncthreads();
    const int c = tid >> 2, rch = (tid & 3) * 16;
    half8 v0 = *(const half8*)&t[c * 72 + rch];
    half8 v1 = *(const half8*)&t[c * 72 + rch + 8];
    _Float16* o = &O[(long)(nb + c) * 1024 + kb + rch];
    *(half8*)o = v0;
    *(half8*)(o + 8) = v1;
}

// ---------------------------------------------------------------------------
// fp32 -> fp16 cast, 8 elems/thread, grid-stride
// ---------------------------------------------------------------------------
__global__ __launch_bounds__(256) void f32_to_f16_kernel(
    const float* __restrict__ in, _Float16* __restrict__ out, int n)
{
    for (long i = ((long)blockIdx.x * 256 + threadIdx.x) * 8; i < n;
         i += (long)gridDim.x * 256 * 8) {
        floatx4 a = *(const floatx4*)&in[i];
        floatx4 b = *(const floatx4*)&in[i + 4];
        half8 h;
#pragma unroll
        for (int e = 0; e < 4; e++) { h[e] = (_Float16)a[e]; h[e + 4] = (_Float16)b[e]; }
        *(half8*)&out[i] = h;
    }
}

// ---------------------------------------------------------------------------
// m97-style GEMM: C[m][n] = sum_k A[m][k] * Bt[n][k]   (both fp16 row-major)
// 128x128 tile, BK=32, 256 threads (4 waves, each a 64x64 quadrant of 4x4
// 16x16x32 MFMAs). global_load_lds width-16 staging, 2-barrier K-loop.
// MODE 0: fp16 out row-major, (+bias)*scale      (projQ/K, scores)
// MODE 1: fp16 out TRANSPOSED per batch (+bias)  (projV -> Vt [d][t])
// MODE 2: fp32 out row-major                     (PV -> d_out)
// ---------------------------------------------------------------------------
template <int MODE>
__global__ __launch_bounds__(256) void gemm128_kernel(
    const _Float16* __restrict__ A, const _Float16* __restrict__ Bt,
    void* __restrict__ Cv, const float* __restrict__ bias,
    int K, int lda, int ldb, int ldc,
    long aBatch, long bBatch, long cBatch, float scale)
{
    __shared__ _Float16 Ash[128 * 32];
    __shared__ _Float16 Bsh[128 * 32];

    const int tid = threadIdx.x;
    const int wave = tid >> 6, lane = tid & 63;
    const int quad = lane >> 4, lr = lane & 15;
    const int wm = wave & 1, wn = wave >> 1;
    const int m0 = blockIdx.y * 128, n0 = blockIdx.x * 128;
    const int z = blockIdx.z;

    const _Float16* Ab = A + (long)z * aBatch;
    const _Float16* Bb = Bt + (long)z * bBatch;

    // staging: thread tid loads 16B; elem offset tid*8 (+2048 for 2nd issue)
    const int srow = tid >> 2;            // 0..63
    const int scol = (tid & 3) * 8;
    const long ag0 = (long)(m0 + srow) * lda + scol;
    const long bg0 = (long)(n0 + srow) * ldb + scol;
    const int sdst = tid * 8;

    floatx4 acc[4][4] = {};

    for (int k0 = 0; k0 < K; k0 += 32) {
        __builtin_amdgcn_global_load_lds(
            (AS1 void*)(Ab + ag0 + k0), (AS3 void*)(Ash + sdst), 16, 0, 0);
        __builtin_amdgcn_global_load_lds(
            (AS1 void*)(Ab + ag0 + (long)64 * lda + k0), (AS3 void*)(Ash + sdst + 2048), 16, 0, 0);
        __builtin_amdgcn_global_load_lds(
            (AS1 void*)(Bb + bg0 + k0), (AS3 void*)(Bsh + sdst), 16, 0, 0);
        __builtin_amdgcn_global_load_lds(
            (AS1 void*)(Bb + bg0 + (long)64 * ldb + k0), (AS3 void*)(Bsh + sdst + 2048), 16, 0, 0);
        __syncthreads();   // drains vmcnt -> LDS data visible

        half8 aF[4], bF[4];
#pragma unroll
        for (int i = 0; i < 4; i++) {
            aF[i] = *(const half8*)&Ash[(wm * 64 + i * 16 + lr) * 32 + quad * 8];
            bF[i] = *(const half8*)&Bsh[(wn * 64 + i * 16 + lr) * 32 + quad * 8];
        }
#pragma unroll
        for (int mi = 0; mi < 4; mi++)
#pragma unroll
            for (int ni = 0; ni < 4; ni++)
                acc[mi][ni] = __builtin_amdgcn_mfma_f32_16x16x32_f16(
                    aF[mi], bF[ni], acc[mi][ni], 0, 0, 0);
        __syncthreads();   // protect LDS before next stage
    }

    // ---- epilogue ----  C/D frag: m = quad*4+reg, n = lane&15
    if constexpr (MODE == 0) {
        _Float16* C = (_Float16*)Cv + (long)z * cBatch;
#pragma unroll
        for (int ni = 0; ni < 4; ni++) {
            const int n = n0 + wn * 64 + ni * 16 + lr;
            const float bv_ = bias ? bias[n] : 0.0f;
#pragma unroll
            for (int mi = 0; mi < 4; mi++) {
                const int mb = m0 + wm * 64 + mi * 16 + quad * 4;
#pragma unroll
                for (int r = 0; r < 4; r++)
                    C[(long)(mb + r) * ldc + n] = (_Float16)((acc[mi][ni][r] + bv_) * scale);
            }
        }
    } else if constexpr (MODE == 1) {
        // transpose through LDS: ctile[n_local][m_local], then coalesced rows
        __shared__ _Float16 ctile[128 * 136];
#pragma unroll
        for (int ni = 0; ni < 4; ni++) {
            const int nl = wn * 64 + ni * 16 + lr;
            const float bv_ = bias ? bias[n0 + nl] : 0.0f;
#pragma unroll
            for (int mi = 0; mi < 4; mi++) {
                const int ml = wm * 64 + mi * 16 + quad * 4;
#pragma unroll
                for (int r = 0; r < 4; r++)
                    ctile[nl * 136 + ml + r] = (_Float16)((acc[mi][ni][r] + bv_) * scale);
            }
        }
        __syncthreads();
        // rows of ctile (fixed d) -> contiguous t in Vt[b][d][t]
        _Float16* C = (_Float16*)Cv + (long)(m0 >> 11) * cBatch;  // batch from m
        const int t0 = m0 & 2047;
#pragma unroll
        for (int p = 0; p < 8; p++) {
            const int row = p * 16 + (tid >> 4);
            const int seg = (tid & 15) * 8;
            half8 v = *(const half8*)&ctile[row * 136 + seg];
            *(half8*)&C[(long)(n0 + row) * ldc + t0 + seg] = v;
        }
    } else {
        float* C = (float*)Cv + (long)z * cBatch;
#pragma unroll
        for (int ni = 0; ni < 4; ni++) {
            const int n = n0 + wn * 64 + ni * 16 + lr;
#pragma unroll
            for (int mi = 0; mi < 4; mi++) {
                const int mb = m0 + wm * 64 + mi * 16 + quad * 4;
#pragma unroll
                for (int r = 0; r < 4; r++)
                    C[(long)(mb + r) * ldc + n] = acc[mi][ni][r] * scale;
            }
        }
    }
}

// ---------------------------------------------------------------------------
// row softmax, in place, fp16. One wave per row of 2048. block=256 -> 4 rows.
// ---------------------------------------------------------------------------
__global__ __launch_bounds__(256) void softmax_kernel(_Float16* __restrict__ buf)
{
    const int lane = threadIdx.x & 63;
    const long row = (long)blockIdx.x * 4 + (threadIdx.x >> 6);
    _Float16* p = buf + row * 2048;

    float f[32];
#pragma unroll
    for (int j = 0; j < 4; j++) {
        half8 v = *(const half8*)&p[lane * 8 + j * 512];
#pragma unroll
        for (int e = 0; e < 8; e++) f[j * 8 + e] = (float)v[e];
    }
    float m = -1e30f;
#pragma unroll
    for (int i = 0; i < 32; i++) m = fmaxf(m, f[i]);
#pragma unroll
    for (int off = 32; off; off >>= 1) m = fmaxf(m, __shfl_xor(m, off, 64));
    float s = 0.0f;
#pragma unroll
    for (int i = 0; i < 32; i++) { f[i] = __expf(f[i] - m); s += f[i]; }
#pragma unroll
    for (int off = 32; off; off >>= 1) s += __shfl_xor(s, off, 64);
    const float inv = 1.0f / s;
#pragma unroll
    for (int j = 0; j < 4; j++) {
        half8 v;
#pragma unroll
        for (int e = 0; e < 8; e++) v[e] = (_Float16)(f[j * 8 + e] * inv);
        *(half8*)&p[lane * 8 + j * 512] = v;
    }
}

// ---------------------------------------------------------------------------
// B=8, S=2048, D=1024.  Workspace layout (bytes):
//   Q   fp16 [16384][1024]            @ 0          (33,554,432)
//   Kb  fp16 [16384][1024]            @ 33,554,432 (33,554,432)
//   Vt  fp16 [8][1024][2048]          @ 67,108,864 (33,554,432)
//   Sc  fp16 [8][2048][2048]          @ 100,663,296 (67,108,864)  (xb aliased here)
//   Wt  fp16 [3][1024][1024]          @ 167,772,160 (6,291,456)
// total 174,063,616
// ---------------------------------------------------------------------------
extern "C" void kernel_launch(void* const* d_in, const int* in_sizes, int n_in,
                              void* d_out, int out_size, void* d_ws, size_t ws_size,
                              hipStream_t stream)
{
    const float* x  = (const float*)d_in[0];
    const float* Wq = (const float*)d_in[1];
    const float* bq = (const float*)d_in[2];
    const float* Wk = (const float*)d_in[3];
    const float* bk = (const float*)d_in[4];
    const float* Wv = (const float*)d_in[5];
    const float* bv = (const float*)d_in[6];

    if (ws_size < 174063616u) return;  // cannot run

    char* ws = (char*)d_ws;
    _Float16* Q  = (_Float16*)(ws + 0);
    _Float16* Kb = (_Float16*)(ws + 33554432);
    _Float16* Vt = (_Float16*)(ws + 67108864);
    _Float16* Sc = (_Float16*)(ws + 100663296);
    _Float16* Wt = (_Float16*)(ws + 167772160);
    _Float16* xb = Sc;  // aliased: xb dead before Sc is written
    float* out = (float*)d_out;

    wtrans_kernel<<<dim3(16, 16, 3), 256, 0, stream>>>(Wq, Wk, Wv, Wt);
    f32_to_f16_kernel<<<2048, 256, 0, stream>>>(x, xb, 16777216);

    // projections: M=16384, N=1024, K=1024
    gemm128_kernel<0><<<dim3(8, 128, 1), 256, 0, stream>>>(
        xb, Wt, Q, bq, 1024, 1024, 1024, 1024, 0, 0, 0, 1.0f);
    gemm128_kernel<0><<<dim3(8, 128, 1), 256, 0, stream>>>(
        xb, Wt + 1048576, Kb, bk, 1024, 1024, 1024, 1024, 0, 0, 0, 1.0f);
    gemm128_kernel<1><<<dim3(8, 128, 1), 256, 0, stream>>>(
        xb, Wt + 2097152, Vt, bv, 1024, 1024, 1024, 2048, 0, 0, 2097152, 1.0f);

    // scores = Q K^T / 32 : per-batch M=N=2048, K=1024
    gemm128_kernel<0><<<dim3(16, 16, 8), 256, 0, stream>>>(
        Q, Kb, Sc, nullptr, 1024, 1024, 1024, 2048,
        2097152, 2097152, 4194304, 0.03125f);

    softmax_kernel<<<4096, 256, 0, stream>>>(Sc);

    // out = P V : per-batch M=2048, N=1024, K=2048
    gemm128_kernel<2><<<dim3(8, 16, 8), 256, 0, stream>>>(
        Sc, Vt, out, nullptr, 2048, 2048, 2048, 1024,
        4194304, 2097152, 2097152, 1.0f);
}

// Round 2
// 491.296 us; speedup vs baseline: 1.1533x; 1.1533x over previous
//
#include <hip/hip_runtime.h>

typedef _Float16 half8 __attribute__((ext_vector_type(8)));
typedef float floatx4 __attribute__((ext_vector_type(4)));

#define AS1 __attribute__((address_space(1)))
#define AS3 __attribute__((address_space(3)))

// ---------------------------------------------------------------------------
// W transpose + fp32->fp16: W [1024][1024] (k,n) -> Wt [1024][1024] (n,k)
// grid (16,16,3), block 256. 64x64 tiles through LDS.
// ---------------------------------------------------------------------------
__global__ __launch_bounds__(256) void wtrans_kernel(
    const float* __restrict__ W0, const float* __restrict__ W1,
    const float* __restrict__ W2, _Float16* __restrict__ Wt)
{
    __shared__ _Float16 t[64 * 72];
    const float* W = (blockIdx.z == 0) ? W0 : (blockIdx.z == 1) ? W1 : W2;
    _Float16* O = Wt + (long)blockIdx.z * 1048576;
    const int tid = threadIdx.x;
    const int kb = blockIdx.y * 64, nb = blockIdx.x * 64;
#pragma unroll
    for (int i = 0; i < 4; i++) {
        int r = (tid >> 4) + i * 16;
        int c = (tid & 15) * 4;
        floatx4 w = *(const floatx4*)&W[(long)(kb + r) * 1024 + nb + c];
#pragma unroll
        for (int j = 0; j < 4; j++) t[(c + j) * 72 + r] = (_Float16)w[j];
    }
    __syncthreads();
    const int c = tid >> 2, rch = (tid & 3) * 16;
    half8 v0 = *(const half8*)&t[c * 72 + rch];
    half8 v1 = *(const half8*)&t[c * 72 + rch + 8];
    _Float16* o = &O[(long)(nb + c) * 1024 + kb + rch];
    *(half8*)o = v0;
    *(half8*)(o + 8) = v1;
}

// ---------------------------------------------------------------------------
// fp32 -> fp16 cast, 8 elems/thread, grid-stride
// ---------------------------------------------------------------------------
__global__ __launch_bounds__(256) void f32_to_f16_kernel(
    const float* __restrict__ in, _Float16* __restrict__ out, int n)
{
    for (long i = ((long)blockIdx.x * 256 + threadIdx.x) * 8; i < n;
         i += (long)gridDim.x * 256 * 8) {
        floatx4 a = *(const floatx4*)&in[i];
        floatx4 b = *(const floatx4*)&in[i + 4];
        half8 h;
#pragma unroll
        for (int e = 0; e < 4; e++) { h[e] = (_Float16)a[e]; h[e + 4] = (_Float16)b[e]; }
        *(half8*)&out[i] = h;
    }
}

// ---------------------------------------------------------------------------
// m97-style GEMM, BK=64 as TWO BK=32 slabs per barrier pair (32 MFMA/barrier).
// C[m][n] = sum_k A[m][k] * Bt[n][k]   (both fp16 row-major)
// 128x128 tile, 256 threads (4 waves, each a 64x64 quadrant of 4x4
// 16x16x32 MFMAs). global_load_lds width-16 staging.
// Each slab keeps the 64B row pitch (rows alternate banks 0/16 -> 2-way,
// free per m136); a monolithic 128B-pitch BK=64 tile would be 16-way.
// MODE 0: fp16 out row-major, (+bias per z)*scale   (projQ/K fused, scores)
// MODE 1: fp16 out TRANSPOSED per batch (+bias)     (projV -> Vt [d][t])
// MODE 2: fp32 out row-major                        (PV -> d_out)
// ---------------------------------------------------------------------------
template <int MODE>
__global__ __launch_bounds__(256) void gemm128_kernel(
    const _Float16* __restrict__ A, const _Float16* __restrict__ Bt,
    void* __restrict__ Cv, const float* __restrict__ bias,
    const float* __restrict__ bias2,
    int K, int lda, int ldb, int ldc,
    long aBatch, long bBatch, long cBatch, float scale)
{
    // tiles: Ash [2 slabs][128x32], Bsh same -> 16384 halves = 32 KB.
    // MODE 1 reuses this LDS for the 128x136 transpose tile (17408 halves).
    constexpr int SMEM_ELEMS = (MODE == 1) ? 17408 : 16384;
    __shared__ _Float16 smem[SMEM_ELEMS];
    _Float16* Ash = smem;
    _Float16* Bsh = smem + 8192;

    const int tid = threadIdx.x;
    const int wave = tid >> 6, lane = tid & 63;
    const int quad = lane >> 4, lr = lane & 15;
    const int wm = wave & 1, wn = wave >> 1;
    const int m0 = blockIdx.y * 128, n0 = blockIdx.x * 128;
    const int z = blockIdx.z;

    const _Float16* Ab = A + (long)z * aBatch;
    const _Float16* Bb = Bt + (long)z * bBatch;

    // staging: thread tid loads 16B; elem offset tid*8 (+2048 for 2nd issue)
    const int srow = tid >> 2;            // 0..63
    const int scol = (tid & 3) * 8;
    const long ag0 = (long)(m0 + srow) * lda + scol;
    const long bg0 = (long)(n0 + srow) * ldb + scol;
    const int sdst = tid * 8;

    floatx4 acc[4][4] = {};

    for (int k0 = 0; k0 < K; k0 += 64) {
#pragma unroll
        for (int s = 0; s < 2; s++) {
            const int kk = k0 + s * 32;
            const int so = s * 4096;
            __builtin_amdgcn_global_load_lds(
                (AS1 void*)(Ab + ag0 + kk), (AS3 void*)(Ash + so + sdst), 16, 0, 0);
            __builtin_amdgcn_global_load_lds(
                (AS1 void*)(Ab + ag0 + (long)64 * lda + kk), (AS3 void*)(Ash + so + sdst + 2048), 16, 0, 0);
            __builtin_amdgcn_global_load_lds(
                (AS1 void*)(Bb + bg0 + kk), (AS3 void*)(Bsh + so + sdst), 16, 0, 0);
            __builtin_amdgcn_global_load_lds(
                (AS1 void*)(Bb + bg0 + (long)64 * ldb + kk), (AS3 void*)(Bsh + so + sdst + 2048), 16, 0, 0);
        }
        __syncthreads();   // drains vmcnt -> LDS data visible

#pragma unroll
        for (int s = 0; s < 2; s++) {
            const int so = s * 4096;
            half8 aF[4], bF[4];
#pragma unroll
            for (int i = 0; i < 4; i++) {
                aF[i] = *(const half8*)&Ash[so + (wm * 64 + i * 16 + lr) * 32 + quad * 8];
                bF[i] = *(const half8*)&Bsh[so + (wn * 64 + i * 16 + lr) * 32 + quad * 8];
            }
#pragma unroll
            for (int mi = 0; mi < 4; mi++)
#pragma unroll
                for (int ni = 0; ni < 4; ni++)
                    acc[mi][ni] = __builtin_amdgcn_mfma_f32_16x16x32_f16(
                        aF[mi], bF[ni], acc[mi][ni], 0, 0, 0);
        }
        __syncthreads();   // protect LDS before next stage
    }

    // ---- epilogue ----  C/D frag: m = quad*4+reg, n = lane&15
    if constexpr (MODE == 0) {
        _Float16* C = (_Float16*)Cv + (long)z * cBatch;
        const float* bz = (z == 0 || !bias2) ? bias : bias2;
#pragma unroll
        for (int ni = 0; ni < 4; ni++) {
            const int n = n0 + wn * 64 + ni * 16 + lr;
            const float bv_ = bz ? bz[n] : 0.0f;
#pragma unroll
            for (int mi = 0; mi < 4; mi++) {
                const int mb = m0 + wm * 64 + mi * 16 + quad * 4;
#pragma unroll
                for (int r = 0; r < 4; r++)
                    C[(long)(mb + r) * ldc + n] = (_Float16)((acc[mi][ni][r] + bv_) * scale);
            }
        }
    } else if constexpr (MODE == 1) {
        // transpose through LDS: ctile[n_local][m_local], then coalesced rows.
        // smem is dead here (trailing __syncthreads of last K-iter passed).
        _Float16* ctile = smem;
#pragma unroll
        for (int ni = 0; ni < 4; ni++) {
            const int nl = wn * 64 + ni * 16 + lr;
            const float bv_ = bias ? bias[n0 + nl] : 0.0f;
#pragma unroll
            for (int mi = 0; mi < 4; mi++) {
                const int ml = wm * 64 + mi * 16 + quad * 4;
#pragma unroll
                for (int r = 0; r < 4; r++)
                    ctile[nl * 136 + ml + r] = (_Float16)((acc[mi][ni][r] + bv_) * scale);
            }
        }
        __syncthreads();
        // rows of ctile (fixed d) -> contiguous t in Vt[b][d][t]
        _Float16* C = (_Float16*)Cv + (long)(m0 >> 11) * cBatch;  // batch from m
        const int t0 = m0 & 2047;
#pragma unroll
        for (int p = 0; p < 8; p++) {
            const int row = p * 16 + (tid >> 4);
            const int seg = (tid & 15) * 8;
            half8 v = *(const half8*)&ctile[row * 136 + seg];
            *(half8*)&C[(long)(n0 + row) * ldc + t0 + seg] = v;
        }
    } else {
        float* C = (float*)Cv + (long)z * cBatch;
#pragma unroll
        for (int ni = 0; ni < 4; ni++) {
            const int n = n0 + wn * 64 + ni * 16 + lr;
#pragma unroll
            for (int mi = 0; mi < 4; mi++) {
                const int mb = m0 + wm * 64 + mi * 16 + quad * 4;
#pragma unroll
                for (int r = 0; r < 4; r++)
                    C[(long)(mb + r) * ldc + n] = acc[mi][ni][r] * scale;
            }
        }
    }
}

// ---------------------------------------------------------------------------
// row softmax, in place, fp16. One wave per row of 2048. block=256 -> 4 rows.
// ---------------------------------------------------------------------------
__global__ __launch_bounds__(256) void softmax_kernel(_Float16* __restrict__ buf)
{
    const int lane = threadIdx.x & 63;
    const long row = (long)blockIdx.x * 4 + (threadIdx.x >> 6);
    _Float16* p = buf + row * 2048;

    float f[32];
#pragma unroll
    for (int j = 0; j < 4; j++) {
        half8 v = *(const half8*)&p[lane * 8 + j * 512];
#pragma unroll
        for (int e = 0; e < 8; e++) f[j * 8 + e] = (float)v[e];
    }
    float m = -1e30f;
#pragma unroll
    for (int i = 0; i < 32; i++) m = fmaxf(m, f[i]);
#pragma unroll
    for (int off = 32; off; off >>= 1) m = fmaxf(m, __shfl_xor(m, off, 64));
    float s = 0.0f;
#pragma unroll
    for (int i = 0; i < 32; i++) { f[i] = __expf(f[i] - m); s += f[i]; }
#pragma unroll
    for (int off = 32; off; off >>= 1) s += __shfl_xor(s, off, 64);
    const float inv = 1.0f / s;
#pragma unroll
    for (int j = 0; j < 4; j++) {
        half8 v;
#pragma unroll
        for (int e = 0; e < 8; e++) v[e] = (_Float16)(f[j * 8 + e] * inv);
        *(half8*)&p[lane * 8 + j * 512] = v;
    }
}

// ---------------------------------------------------------------------------
// B=8, S=2048, D=1024.  Workspace layout (bytes):
//   Q   fp16 [16384][1024]            @ 0          (33,554,432)
//   Kb  fp16 [16384][1024]            @ 33,554,432 (33,554,432)   (contig w/ Q)
//   Vt  fp16 [8][1024][2048]          @ 67,108,864 (33,554,432)
//   Sc  fp16 [8][2048][2048]          @ 100,663,296 (67,108,864)  (xb aliased)
//   Wt  fp16 [3][1024][1024]          @ 167,772,160 (6,291,456)
// total 174,063,616
// ---------------------------------------------------------------------------
extern "C" void kernel_launch(void* const* d_in, const int* in_sizes, int n_in,
                              void* d_out, int out_size, void* d_ws, size_t ws_size,
                              hipStream_t stream)
{
    const float* x  = (const float*)d_in[0];
    const float* Wq = (const float*)d_in[1];
    const float* bq = (const float*)d_in[2];
    const float* Wk = (const float*)d_in[3];
    const float* bk = (const float*)d_in[4];
    const float* Wv = (const float*)d_in[5];
    const float* bv = (const float*)d_in[6];

    if (ws_size < 174063616u) return;  // cannot run

    char* ws = (char*)d_ws;
    _Float16* Q  = (_Float16*)(ws + 0);
    _Float16* Vt = (_Float16*)(ws + 67108864);
    _Float16* Sc = (_Float16*)(ws + 100663296);
    _Float16* Wt = (_Float16*)(ws + 167772160);
    _Float16* xb = Sc;  // aliased: xb dead before Sc is written
    _Float16* Kb = Q + 16777216;
    float* out = (float*)d_out;

    wtrans_kernel<<<dim3(16, 16, 3), 256, 0, stream>>>(Wq, Wk, Wv, Wt);
    f32_to_f16_kernel<<<2048, 256, 0, stream>>>(x, xb, 16777216);

    // Q and K projections fused via z: M=16384, N=1024, K=1024
    gemm128_kernel<0><<<dim3(8, 128, 2), 256, 0, stream>>>(
        xb, Wt, Q, bq, bk, 1024, 1024, 1024, 1024,
        0, 1048576, 16777216, 1.0f);
    // V projection -> Vt [b][d][t]
    gemm128_kernel<1><<<dim3(8, 128, 1), 256, 0, stream>>>(
        xb, Wt + 2097152, Vt, bv, nullptr, 1024, 1024, 1024, 2048,
        0, 0, 2097152, 1.0f);

    // scores = Q K^T / 32 : per-batch M=N=2048, K=1024
    gemm128_kernel<0><<<dim3(16, 16, 8), 256, 0, stream>>>(
        Q, Kb, Sc, nullptr, nullptr, 1024, 1024, 1024, 2048,
        2097152, 2097152, 4194304, 0.03125f);

    softmax_kernel<<<4096, 256, 0, stream>>>(Sc);

    // out = P V : per-batch M=2048, N=1024, K=2048
    gemm128_kernel<2><<<dim3(8, 16, 8), 256, 0, stream>>>(
        Sc, Vt, out, nullptr, nullptr, 2048, 2048, 2048, 1024,
        4194304, 2097152, 2097152, 1.0f);
}

// Round 3
// 461.626 us; speedup vs baseline: 1.2275x; 1.0643x over previous
//
#include <hip/hip_runtime.h>

typedef _Float16 half8 __attribute__((ext_vector_type(8)));
typedef float floatx4 __attribute__((ext_vector_type(4)));

#define AS1 __attribute__((address_space(1)))
#define AS3 __attribute__((address_space(3)))

// ---------------------------------------------------------------------------
// W transpose + fp32->fp16: W [1024][1024] (k,n) -> Wt [1024][1024] (n,k)
// grid (16,16,3), block 256. 64x64 tiles through LDS.
// ---------------------------------------------------------------------------
__global__ __launch_bounds__(256) void wtrans_kernel(
    const float* __restrict__ W0, const float* __restrict__ W1,
    const float* __restrict__ W2, _Float16* __restrict__ Wt)
{
    __shared__ _Float16 t[64 * 72];
    const float* W = (blockIdx.z == 0) ? W0 : (blockIdx.z == 1) ? W1 : W2;
    _Float16* O = Wt + (long)blockIdx.z * 1048576;
    const int tid = threadIdx.x;
    const int kb = blockIdx.y * 64, nb = blockIdx.x * 64;
#pragma unroll
    for (int i = 0; i < 4; i++) {
        int r = (tid >> 4) + i * 16;
        int c = (tid & 15) * 4;
        floatx4 w = *(const floatx4*)&W[(long)(kb + r) * 1024 + nb + c];
#pragma unroll
        for (int j = 0; j < 4; j++) t[(c + j) * 72 + r] = (_Float16)w[j];
    }
    __syncthreads();
    const int c = tid >> 2, rch = (tid & 3) * 16;
    half8 v0 = *(const half8*)&t[c * 72 + rch];
    half8 v1 = *(const half8*)&t[c * 72 + rch + 8];
    _Float16* o = &O[(long)(nb + c) * 1024 + kb + rch];
    *(half8*)o = v0;
    *(half8*)(o + 8) = v1;
}

// ---------------------------------------------------------------------------
// fp32 -> fp16 cast, 8 elems/thread, grid-stride
// ---------------------------------------------------------------------------
__global__ __launch_bounds__(256) void f32_to_f16_kernel(
    const float* __restrict__ in, _Float16* __restrict__ out, int n)
{
    for (long i = ((long)blockIdx.x * 256 + threadIdx.x) * 8; i < n;
         i += (long)gridDim.x * 256 * 8) {
        floatx4 a = *(const floatx4*)&in[i];
        floatx4 b = *(const floatx4*)&in[i + 4];
        half8 h;
#pragma unroll
        for (int e = 0; e < 4; e++) { h[e] = (_Float16)a[e]; h[e + 4] = (_Float16)b[e]; }
        *(half8*)&out[i] = h;
    }
}

// ---------------------------------------------------------------------------
// m97-style GEMM, BK=64 (two BK=32 slabs per barrier pair, 32 MFMA/barrier).
// C[m][n] = sum_k A[m][k] * Bt[n][k]   (both fp16 row-major)
// 128x128 tile, 256 threads (4 waves, 4x4 16x16x32 MFMAs each).
//
// XCD-aware swizzle: 1D grid, bid&7 = XCD (HW round-robins consecutive ids
// across the 8 XCDs), bid>>3 = slot. g = xcd*(T/8)+slot decoded as
// (z, y, x) gives each XCD a CONTIGUOUS (z, y-slab) region -> B panels and
// A strips stay in that XCD's 4 MB L2 instead of being fetched by all 8.
// Perf heuristic only — correctness independent of the XCD mapping.
//
// MODE 0: fp16 out row-major, (+bias per z)*scale   (projQ/K fused, scores)
// MODE 1: fp16 out TRANSPOSED per batch (+bias)     (projV -> Vt [d][t])
// MODE 2: fp32 out row-major                        (PV -> d_out)
// ---------------------------------------------------------------------------
template <int MODE>
__global__ __launch_bounds__(256) void gemm128_kernel(
    const _Float16* __restrict__ A, const _Float16* __restrict__ Bt,
    void* __restrict__ Cv, const float* __restrict__ bias,
    const float* __restrict__ bias2,
    int nx, int ny,
    int K, int lda, int ldb, int ldc,
    long aBatch, long bBatch, long cBatch, float scale)
{
    constexpr int SMEM_ELEMS = (MODE == 1) ? 17408 : 16384;
    __shared__ _Float16 smem[SMEM_ELEMS];
    _Float16* Ash = smem;
    _Float16* Bsh = smem + 8192;

    const int tid = threadIdx.x;
    const int wave = tid >> 6, lane = tid & 63;
    const int quad = lane >> 4, lr = lane & 15;
    const int wm = wave & 1, wn = wave >> 1;

    // ---- XCD swizzle ----
    const int P = gridDim.x >> 3;                 // blocks per XCD
    const int g = (blockIdx.x & 7) * P + (blockIdx.x >> 3);
    const int pplane = nx * ny;
    const int z = g / pplane;
    const int rr = g - z * pplane;
    const int by = rr / nx;
    const int bx = rr - by * nx;
    const int m0 = by * 128, n0 = bx * 128;

    const _Float16* Ab = A + (long)z * aBatch;
    const _Float16* Bb = Bt + (long)z * bBatch;

    // staging: thread tid loads 16B; elem offset tid*8 (+2048 for 2nd issue)
    const int srow = tid >> 2;            // 0..63
    const int scol = (tid & 3) * 8;
    const long ag0 = (long)(m0 + srow) * lda + scol;
    const long bg0 = (long)(n0 + srow) * ldb + scol;
    const int sdst = tid * 8;

    floatx4 acc[4][4] = {};

    for (int k0 = 0; k0 < K; k0 += 64) {
#pragma unroll
        for (int s = 0; s < 2; s++) {
            const int kk = k0 + s * 32;
            const int so = s * 4096;
            __builtin_amdgcn_global_load_lds(
                (AS1 void*)(Ab + ag0 + kk), (AS3 void*)(Ash + so + sdst), 16, 0, 0);
            __builtin_amdgcn_global_load_lds(
                (AS1 void*)(Ab + ag0 + (long)64 * lda + kk), (AS3 void*)(Ash + so + sdst + 2048), 16, 0, 0);
            __builtin_amdgcn_global_load_lds(
                (AS1 void*)(Bb + bg0 + kk), (AS3 void*)(Bsh + so + sdst), 16, 0, 0);
            __builtin_amdgcn_global_load_lds(
                (AS1 void*)(Bb + bg0 + (long)64 * ldb + kk), (AS3 void*)(Bsh + so + sdst + 2048), 16, 0, 0);
        }
        __syncthreads();   // drains vmcnt -> LDS data visible

#pragma unroll
        for (int s = 0; s < 2; s++) {
            const int so = s * 4096;
            half8 aF[4], bF[4];
#pragma unroll
            for (int i = 0; i < 4; i++) {
                aF[i] = *(const half8*)&Ash[so + (wm * 64 + i * 16 + lr) * 32 + quad * 8];
                bF[i] = *(const half8*)&Bsh[so + (wn * 64 + i * 16 + lr) * 32 + quad * 8];
            }
#pragma unroll
            for (int mi = 0; mi < 4; mi++)
#pragma unroll
                for (int ni = 0; ni < 4; ni++)
                    acc[mi][ni] = __builtin_amdgcn_mfma_f32_16x16x32_f16(
                        aF[mi], bF[ni], acc[mi][ni], 0, 0, 0);
        }
        __syncthreads();   // protect LDS before next stage
    }

    // ---- epilogue ----  C/D frag: m = quad*4+reg, n = lane&15
    if constexpr (MODE == 0) {
        _Float16* C = (_Float16*)Cv + (long)z * cBatch;
        const float* bz = (z == 0 || !bias2) ? bias : bias2;
#pragma unroll
        for (int ni = 0; ni < 4; ni++) {
            const int n = n0 + wn * 64 + ni * 16 + lr;
            const float bv_ = bz ? bz[n] : 0.0f;
#pragma unroll
            for (int mi = 0; mi < 4; mi++) {
                const int mb = m0 + wm * 64 + mi * 16 + quad * 4;
#pragma unroll
                for (int r = 0; r < 4; r++)
                    C[(long)(mb + r) * ldc + n] = (_Float16)((acc[mi][ni][r] + bv_) * scale);
            }
        }
    } else if constexpr (MODE == 1) {
        // transpose through LDS: ctile[n_local][m_local], then coalesced rows.
        _Float16* ctile = smem;
#pragma unroll
        for (int ni = 0; ni < 4; ni++) {
            const int nl = wn * 64 + ni * 16 + lr;
            const float bv_ = bias ? bias[n0 + nl] : 0.0f;
#pragma unroll
            for (int mi = 0; mi < 4; mi++) {
                const int ml = wm * 64 + mi * 16 + quad * 4;
#pragma unroll
                for (int r = 0; r < 4; r++)
                    ctile[nl * 136 + ml + r] = (_Float16)((acc[mi][ni][r] + bv_) * scale);
            }
        }
        __syncthreads();
        // rows of ctile (fixed d) -> contiguous t in Vt[b][d][t]
        _Float16* C = (_Float16*)Cv + (long)(m0 >> 11) * cBatch;  // batch from m
        const int t0 = m0 & 2047;
#pragma unroll
        for (int p = 0; p < 8; p++) {
            const int row = p * 16 + (tid >> 4);
            const int seg = (tid & 15) * 8;
            half8 v = *(const half8*)&ctile[row * 136 + seg];
            *(half8*)&C[(long)(n0 + row) * ldc + t0 + seg] = v;
        }
    } else {
        float* C = (float*)Cv + (long)z * cBatch;
#pragma unroll
        for (int ni = 0; ni < 4; ni++) {
            const int n = n0 + wn * 64 + ni * 16 + lr;
#pragma unroll
            for (int mi = 0; mi < 4; mi++) {
                const int mb = m0 + wm * 64 + mi * 16 + quad * 4;
#pragma unroll
                for (int r = 0; r < 4; r++)
                    C[(long)(mb + r) * ldc + n] = acc[mi][ni][r] * scale;
            }
        }
    }
}

// ---------------------------------------------------------------------------
// row softmax, in place, fp16. One wave per row of 2048. block=256 -> 4 rows.
// ---------------------------------------------------------------------------
__global__ __launch_bounds__(256) void softmax_kernel(_Float16* __restrict__ buf)
{
    const int lane = threadIdx.x & 63;
    const long row = (long)blockIdx.x * 4 + (threadIdx.x >> 6);
    _Float16* p = buf + row * 2048;

    float f[32];
#pragma unroll
    for (int j = 0; j < 4; j++) {
        half8 v = *(const half8*)&p[lane * 8 + j * 512];
#pragma unroll
        for (int e = 0; e < 8; e++) f[j * 8 + e] = (float)v[e];
    }
    float m = -1e30f;
#pragma unroll
    for (int i = 0; i < 32; i++) m = fmaxf(m, f[i]);
#pragma unroll
    for (int off = 32; off; off >>= 1) m = fmaxf(m, __shfl_xor(m, off, 64));
    float s = 0.0f;
#pragma unroll
    for (int i = 0; i < 32; i++) { f[i] = __expf(f[i] - m); s += f[i]; }
#pragma unroll
    for (int off = 32; off; off >>= 1) s += __shfl_xor(s, off, 64);
    const float inv = 1.0f / s;
#pragma unroll
    for (int j = 0; j < 4; j++) {
        half8 v;
#pragma unroll
        for (int e = 0; e < 8; e++) v[e] = (_Float16)(f[j * 8 + e] * inv);
        *(half8*)&p[lane * 8 + j * 512] = v;
    }
}

// ---------------------------------------------------------------------------
// B=8, S=2048, D=1024.  Workspace layout (bytes):
//   Q   fp16 [16384][1024]            @ 0          (33,554,432)
//   Kb  fp16 [16384][1024]            @ 33,554,432 (33,554,432)   (contig w/ Q)
//   Vt  fp16 [8][1024][2048]          @ 67,108,864 (33,554,432)
//   Sc  fp16 [8][2048][2048]          @ 100,663,296 (67,108,864)  (xb aliased)
//   Wt  fp16 [3][1024][1024]          @ 167,772,160 (6,291,456)
// total 174,063,616
// ---------------------------------------------------------------------------
extern "C" void kernel_launch(void* const* d_in, const int* in_sizes, int n_in,
                              void* d_out, int out_size, void* d_ws, size_t ws_size,
                              hipStream_t stream)
{
    const float* x  = (const float*)d_in[0];
    const float* Wq = (const float*)d_in[1];
    const float* bq = (const float*)d_in[2];
    const float* Wk = (const float*)d_in[3];
    const float* bk = (const float*)d_in[4];
    const float* Wv = (const float*)d_in[5];
    const float* bv = (const float*)d_in[6];

    if (ws_size < 174063616u) return;  // cannot run

    char* ws = (char*)d_ws;
    _Float16* Q  = (_Float16*)(ws + 0);
    _Float16* Vt = (_Float16*)(ws + 67108864);
    _Float16* Sc = (_Float16*)(ws + 100663296);
    _Float16* Wt = (_Float16*)(ws + 167772160);
    _Float16* xb = Sc;  // aliased: xb dead before Sc is written
    _Float16* Kb = Q + 16777216;
    float* out = (float*)d_out;

    wtrans_kernel<<<dim3(16, 16, 3), 256, 0, stream>>>(Wq, Wk, Wv, Wt);
    f32_to_f16_kernel<<<2048, 256, 0, stream>>>(x, xb, 16777216);

    // Q and K projections fused via z: M=16384, N=1024, K=1024, 2048 blocks
    gemm128_kernel<0><<<2048, 256, 0, stream>>>(
        xb, Wt, Q, bq, bk, 8, 128, 1024, 1024, 1024, 1024,
        0, 1048576, 16777216, 1.0f);
    // V projection -> Vt [b][d][t], 1024 blocks
    gemm128_kernel<1><<<1024, 256, 0, stream>>>(
        xb, Wt + 2097152, Vt, bv, nullptr, 8, 128, 1024, 1024, 1024, 2048,
        0, 0, 2097152, 1.0f);

    // scores = Q K^T / 32 : per-batch M=N=2048, K=1024, 2048 blocks (z=XCD)
    gemm128_kernel<0><<<2048, 256, 0, stream>>>(
        Q, Kb, Sc, nullptr, nullptr, 16, 16, 1024, 1024, 1024, 2048,
        2097152, 2097152, 4194304, 0.03125f);

    softmax_kernel<<<4096, 256, 0, stream>>>(Sc);

    // out = P V : per-batch M=2048, N=1024, K=2048, 1024 blocks (z=XCD)
    gemm128_kernel<2><<<1024, 256, 0, stream>>>(
        Sc, Vt, out, nullptr, nullptr, 8, 16, 2048, 2048, 2048, 1024,
        4194304, 2097152, 2097152, 1.0f);
}